// Round 4
// baseline (319.212 us; speedup 1.0000x reference)
//
#include <hip/hip_runtime.h>
#include <math.h>

#define N_NODE 20000
#define N_EDGE 200000
#define EMBED 256
#define PAIR 128
#define HEADS 16
#define HEAD_DIM 16
#define SCALING 0.25f
#define LNEPS 1e-5f

typedef unsigned short u16;
typedef unsigned int u32;
typedef __attribute__((ext_vector_type(8))) short bf16x8;
typedef __attribute__((ext_vector_type(4))) float f32x4;

// ---------------- workspace layout (bytes) ----------------
#define WS_QKV   0            // qkv_bf : 20000*768*2  = 30,720,000 (q scaled)
#define WS_QN    30720000     // qn_bf  : 20000*256*2  = 10,240,000
#define WS_WBF   40960000     // Wbf    : 768*256*2    =    393,216
#define WS_WW    41353216     // WW_bf  : 16*128*2     =      4,096
#define WS_C0    41357312     // c0     : 16*4 (pad 64)
#define WS_C1    41357376     // c1     : 16*4 (pad 64)
#define WS_BIAS  41357440     // bias   : 200000*16*4  = 12,800,000
#define WS_VW    54157440     // vw     : 20000*48*4   =  3,840,000
#define WS_CNT   57997440     // counts : 20000*4
#define WS_CUR   58077440     // cursor : 20000*4
#define WS_OFF   58157440     // off    : 20001*4 (pad to 80064)
#define WS_DE    58237504     // {dst,e}: 200000*8     =  1,600,000

__device__ __forceinline__ u16 f2bf(float f) {
  u32 u = __float_as_uint(f);
  u32 r = (u + 0x7FFFu + ((u >> 16) & 1u)) >> 16;
  return (u16)r;
}
__device__ __forceinline__ float bl(u32 u) { return __uint_as_float(u << 16); }
__device__ __forceinline__ float bh(u32 u) { return __uint_as_float(u & 0xFFFF0000u); }

__device__ __forceinline__ float dot8(uint4 a, uint4 b) {
  float s = bl(a.x) * bl(b.x) + bh(a.x) * bh(b.x);
  s += bl(a.y) * bl(b.y) + bh(a.y) * bh(b.y);
  s += bl(a.z) * bl(b.z) + bh(a.z) * bh(b.z);
  s += bl(a.w) * bl(b.w) + bh(a.w) * bh(b.w);
  return s;
}

// ------------------------------------------------------------------
// K1: per-node LN -> qn_bf. One wave per node. Also zeroes CSR counters.
__global__ __launch_bounds__(256) void ln_qn_kernel(
    const float* __restrict__ query, const float* __restrict__ ln_w,
    const float* __restrict__ ln_b, u16* __restrict__ qn,
    int* __restrict__ counts, int* __restrict__ cur) {
  int z = blockIdx.x * 256 + threadIdx.x;
  if (z < N_NODE) { counts[z] = 0; cur[z] = 0; }
  int node = blockIdx.x * 4 + (threadIdx.x >> 6);
  int lane = threadIdx.x & 63;
  float4 a = *(const float4*)(query + (size_t)node * EMBED + lane * 4);
  float s = a.x + a.y + a.z + a.w;
  float s2 = a.x * a.x + a.y * a.y + a.z * a.z + a.w * a.w;
  #pragma unroll
  for (int off = 32; off > 0; off >>= 1) {
    s += __shfl_xor(s, off);
    s2 += __shfl_xor(s2, off);
  }
  float m = s * (1.0f / EMBED);
  float r = rsqrtf(s2 * (1.0f / EMBED) - m * m + LNEPS);
  float4 w4 = *(const float4*)(ln_w + lane * 4);
  float4 b4 = *(const float4*)(ln_b + lane * 4);
  ushort4 st;
  st.x = f2bf((a.x - m) * r * w4.x + b4.x);
  st.y = f2bf((a.y - m) * r * w4.y + b4.y);
  st.z = f2bf((a.z - m) * r * w4.z + b4.z);
  st.w = f2bf((a.w - m) * r * w4.w + b4.w);
  *(ushort4*)(qn + (size_t)node * EMBED + lane * 4) = st;
}

// ------------------------------------------------------------------
// K2: Wq|Wk|Wv -> Wbf (768x256 bf16), row j = output feature j.
__global__ __launch_bounds__(256) void wcvt_kernel(
    const float* __restrict__ Wq, const float* __restrict__ Wk,
    const float* __restrict__ Wv, u16* __restrict__ Wbf) {
  int g4 = blockIdx.x * 256 + threadIdx.x;
  int idx = g4 * 4;
  const float* src = (idx < 65536) ? Wq : (idx < 131072 ? Wk : Wv);
  float4 v = *(const float4*)(src + (idx & 65535));
  ushort4 st = {f2bf(v.x), f2bf(v.y), f2bf(v.z), f2bf(v.w)};
  *(ushort4*)(Wbf + idx) = st;
}

// ------------------------------------------------------------------
// K3: WW_bf[h][i] = bf16(plw[i]*Wb[h][i]); c1[h]=sum WW; c0[h]=sum plb*Wb + bb.
__global__ __launch_bounds__(64) void prep_kernel(
    const float* __restrict__ pln_w, const float* __restrict__ pln_b,
    const float* __restrict__ Wb, const float* __restrict__ bb,
    u16* __restrict__ WWbf, float* __restrict__ c0, float* __restrict__ c1) {
  int h = blockIdx.x, l = threadIdx.x;
  int i0 = l * 2;
  float wb0 = Wb[h * PAIR + i0], wb1 = Wb[h * PAIR + i0 + 1];
  float ww0 = pln_w[i0] * wb0, ww1 = pln_w[i0 + 1] * wb1;
  WWbf[h * PAIR + i0] = f2bf(ww0);
  WWbf[h * PAIR + i0 + 1] = f2bf(ww1);
  float s1 = ww0 + ww1;
  float s0 = pln_b[i0] * wb0 + pln_b[i0 + 1] * wb1;
  #pragma unroll
  for (int off = 32; off > 0; off >>= 1) {
    s1 += __shfl_xor(s1, off);
    s0 += __shfl_xor(s0, off);
  }
  if (l == 0) {
    c1[h] = s1;
    c0[h] = s0 + bb[h];
  }
}

// ------------------------------------------------------------------
// K4: bf16 MFMA GEMM (R2-proven): qkv[n][j] = qn[n].Wbf[j], j in 0..767.
// 64x64 tile, full K=256 staged once. LDS rows padded to 264 ushorts.
#define GP 264
__global__ __launch_bounds__(256, 2) void qkv_gemm_kernel(
    const u16* __restrict__ qn, const u16* __restrict__ Wbf,
    u16* __restrict__ qkv) {
  __shared__ u16 As[64 * GP];
  __shared__ u16 Bs[64 * GP];
  int t = threadIdx.x;
  int wv = t >> 6, lane = t & 63;
  int quad = lane >> 4, l16 = lane & 15;
  int row0 = blockIdx.x * 64, col0 = blockIdx.y * 64;
  #pragma unroll
  for (int j = 0; j < 8; j++) {
    int row = j * 8 + (t >> 5);
    int slot = t & 31;
    int ra = min(row0 + row, N_NODE - 1);
    uint4 va = *(const uint4*)(qn + (size_t)ra * 256 + slot * 8);
    *(uint4*)(&As[row * GP + slot * 8]) = va;
    uint4 vb = *(const uint4*)(Wbf + (size_t)(col0 + row) * 256 + slot * 8);
    *(uint4*)(&Bs[row * GP + slot * 8]) = vb;
  }
  __syncthreads();
  int mt = (wv >> 1) * 32, nt = (wv & 1) * 32;
  f32x4 acc[2][2];
  #pragma unroll
  for (int im = 0; im < 2; im++)
    #pragma unroll
    for (int in_ = 0; in_ < 2; in_++) acc[im][in_] = (f32x4){0.f, 0.f, 0.f, 0.f};
  #pragma unroll
  for (int sk = 0; sk < 8; sk++) {
    int ko = sk * 32 + quad * 8;
    bf16x8 a0 = *(const bf16x8*)(&As[(mt + l16) * GP + ko]);
    bf16x8 a1 = *(const bf16x8*)(&As[(mt + 16 + l16) * GP + ko]);
    bf16x8 b0 = *(const bf16x8*)(&Bs[(nt + l16) * GP + ko]);
    bf16x8 b1 = *(const bf16x8*)(&Bs[(nt + 16 + l16) * GP + ko]);
    acc[0][0] = __builtin_amdgcn_mfma_f32_16x16x32_bf16(a0, b0, acc[0][0], 0, 0, 0);
    acc[0][1] = __builtin_amdgcn_mfma_f32_16x16x32_bf16(a0, b1, acc[0][1], 0, 0, 0);
    acc[1][0] = __builtin_amdgcn_mfma_f32_16x16x32_bf16(a1, b0, acc[1][0], 0, 0, 0);
    acc[1][1] = __builtin_amdgcn_mfma_f32_16x16x32_bf16(a1, b1, acc[1][1], 0, 0, 0);
  }
  float scale = (col0 < 256) ? SCALING : 1.0f;
  #pragma unroll
  for (int im = 0; im < 2; im++) {
    #pragma unroll
    for (int in_ = 0; in_ < 2; in_++) {
      #pragma unroll
      for (int r = 0; r < 4; r++) {
        int grow = row0 + mt + im * 16 + quad * 4 + r;
        int gcol = col0 + nt + in_ * 16 + l16;
        if (grow < N_NODE)
          qkv[(size_t)grow * 768 + gcol] = f2bf(acc[im][in_][r] * scale);
      }
    }
  }
}

// ------------------------------------------------------------------
// K5: vw[n][h][c] = sum_d v[n,h*16+d]*Wf_c[h*16+d] (R2-proven).
__global__ __launch_bounds__(256) void vw_kernel(
    const u16* __restrict__ qkv, const float* __restrict__ Wf1,
    const float* __restrict__ Wf2, const float* __restrict__ Wf3,
    float* __restrict__ vw) {
  int gid = blockIdx.x * 256 + threadIdx.x;  // 320000
  int n = gid >> 4, h = gid & 15;
  const uint4* vp = (const uint4*)(qkv + (size_t)n * 768 + 512 + h * 16);
  uint4 va = vp[0], vb = vp[1];
  float v[16];
  v[0] = bl(va.x); v[1] = bh(va.x); v[2] = bl(va.y); v[3] = bh(va.y);
  v[4] = bl(va.z); v[5] = bh(va.z); v[6] = bl(va.w); v[7] = bh(va.w);
  v[8] = bl(vb.x); v[9] = bh(vb.x); v[10] = bl(vb.y); v[11] = bh(vb.y);
  v[12] = bl(vb.z); v[13] = bh(vb.z); v[14] = bl(vb.w); v[15] = bh(vb.w);
  const float* wf[3] = {Wf1 + h * 16, Wf2 + h * 16, Wf3 + h * 16};
  #pragma unroll
  for (int c = 0; c < 3; c++) {
    float s = 0.f;
    #pragma unroll
    for (int d = 0; d < 16; d++) s += v[d] * wf[c][d];
    vw[(size_t)n * 48 + h * 3 + c] = s;
  }
}

// ------------------------------------------------------------------
// K6: pair bias via MFMA (R2-proven): bias[e][h] = r_e*(p.WW_h - m_e*c1_h)+c0_h.
#define PP 136
__global__ __launch_bounds__(256) void pair_bias_kernel(
    const float* __restrict__ pair, const u16* __restrict__ WWbf,
    const float* __restrict__ c0g, const float* __restrict__ c1g,
    float* __restrict__ bias) {
  __shared__ u16 Ps[64 * PP];
  __shared__ u16 WWs[16 * PP];
  __shared__ float ms[64], rs[64], c0s[16], c1s[16];
  int t = threadIdx.x;
  int wv = t >> 6, lane = t & 63;
  int quad = lane >> 4, l16 = lane & 15;
  int e0 = blockIdx.x * 64;
  #pragma unroll
  for (int j = 0; j < 8; j++) {
    int L = j * 256 + t;
    int row = L >> 5, slot = L & 31;
    float4 p = *(const float4*)(pair + (size_t)(e0 + row) * PAIR + slot * 4);
    ushort4 st = {f2bf(p.x), f2bf(p.y), f2bf(p.z), f2bf(p.w)};
    *(ushort4*)(&Ps[row * PP + slot * 4]) = st;
  }
  #pragma unroll
  for (int j = 0; j < 2; j++) {
    int L = j * 256 + t;
    int row = L >> 5, slot = L & 31;
    ushort4 w = *(const ushort4*)(WWbf + row * PAIR + slot * 4);
    *(ushort4*)(&WWs[row * PP + slot * 4]) = w;
  }
  if (t < 16) {
    c0s[t] = c0g[t];
    c1s[t] = c1g[t];
  }
  __syncthreads();
  {
    int row = t >> 2, qq = t & 3;
    float s = 0.f, s2 = 0.f;
    #pragma unroll
    for (int jj = 0; jj < 8; jj++) {
      ushort4 u = *(const ushort4*)(&Ps[row * PP + (qq * 8 + jj) * 4]);
      float x0 = __uint_as_float((u32)u.x << 16);
      float x1 = __uint_as_float((u32)u.y << 16);
      float x2 = __uint_as_float((u32)u.z << 16);
      float x3 = __uint_as_float((u32)u.w << 16);
      s += x0 + x1 + x2 + x3;
      s2 += x0 * x0 + x1 * x1 + x2 * x2 + x3 * x3;
    }
    s += __shfl_xor(s, 1); s += __shfl_xor(s, 2);
    s2 += __shfl_xor(s2, 1); s2 += __shfl_xor(s2, 2);
    if (qq == 0) {
      float m = s * (1.0f / PAIR);
      ms[row] = m;
      rs[row] = rsqrtf(s2 * (1.0f / PAIR) - m * m + LNEPS);
    }
  }
  __syncthreads();
  f32x4 acc = (f32x4){0.f, 0.f, 0.f, 0.f};
  #pragma unroll
  for (int sk = 0; sk < 4; sk++) {
    int ko = sk * 32 + quad * 8;
    bf16x8 a = *(const bf16x8*)(&Ps[(wv * 16 + l16) * PP + ko]);
    bf16x8 b = *(const bf16x8*)(&WWs[l16 * PP + ko]);
    acc = __builtin_amdgcn_mfma_f32_16x16x32_bf16(a, b, acc, 0, 0, 0);
  }
  #pragma unroll
  for (int r = 0; r < 4; r++) {
    int el = wv * 16 + quad * 4 + r;
    float bv = rs[el] * (acc[r] - ms[el] * c1s[l16]) + c0s[l16];
    bias[(size_t)(e0 + el) * HEADS + l16] = bv;
  }
}

// ------------------------------------------------------------------
// K7: histogram of src.
__global__ __launch_bounds__(256) void hist_kernel(
    const int* __restrict__ edge_index, int* __restrict__ counts) {
  int e = blockIdx.x * 256 + threadIdx.x;
  if (e < N_EDGE) atomicAdd(&counts[edge_index[e * 2]], 1);
}

// ------------------------------------------------------------------
// K8: exclusive scan of counts (20000) -> off[0..20000]. Single block.
__global__ __launch_bounds__(1024) void scan_kernel(
    const int* __restrict__ counts, int* __restrict__ off) {
  __shared__ int part[1024];
  int t = threadIdx.x;
  int loc[20];
  int s = 0;
  #pragma unroll
  for (int i = 0; i < 20; i++) {
    int idx = t * 20 + i;
    int v = (idx < N_NODE) ? counts[idx] : 0;
    loc[i] = s;
    s += v;
  }
  part[t] = s;
  __syncthreads();
  int x = s;
  for (int o = 1; o < 1024; o <<= 1) {
    int y = (t >= o) ? part[t - o] : 0;
    __syncthreads();
    x += y;
    part[t] = x;
    __syncthreads();
  }
  int excl = x - s;
  #pragma unroll
  for (int i = 0; i < 20; i++) {
    int idx = t * 20 + i;
    if (idx < N_NODE) off[idx] = excl + loc[i];
  }
  if (t == 0) off[N_NODE] = N_EDGE;
}

// ------------------------------------------------------------------
// K9: scatter edges into CSR order: de[pos] = {dst, e}.
__global__ __launch_bounds__(256) void scatter_kernel(
    const int* __restrict__ edge_index, const int* __restrict__ off,
    int* __restrict__ cur, int2* __restrict__ de) {
  int e = blockIdx.x * 256 + threadIdx.x;
  if (e >= N_EDGE) return;
  int src = edge_index[e * 2 + 0];
  int dst = edge_index[e * 2 + 1];
  int pos = off[src] + atomicAdd(&cur[src], 1);
  de[pos] = make_int2(dst, e);
}

// ------------------------------------------------------------------
// K10: segmented attention, one wave per src node, lane = (h, eslot).
// No LDS, no degree cap: pass 1 sums exp into per-head denom (register
// butterfly), pass 2 recomputes exp (bit-identical args) and accumulates
// sum_{e,h} diff_ec * prob * vw[dst,h,c]. Plain store — no atomics.
__global__ __launch_bounds__(256) void seg_attn_kernel(
    const u16* __restrict__ qkv, const float* __restrict__ bias,
    const int* __restrict__ off, const int2* __restrict__ de,
    const float* __restrict__ vw, const float* __restrict__ edge_diff,
    const float* __restrict__ bf1, const float* __restrict__ bf2,
    const float* __restrict__ bf3, float* __restrict__ out) {
  int wv = threadIdx.x >> 6, lane = threadIdx.x & 63;
  int src = blockIdx.x * 4 + wv;
  int h = lane & 15, eslot = lane >> 4;
  int lo = off[src];
  int deg = off[src + 1] - lo;
  const uint4* qp = (const uint4*)(qkv + (size_t)src * 768 + h * 16);
  uint4 q0 = qp[0], q1 = qp[1];
  float exsum = 0.f;
  for (int ei = eslot; ei < deg; ei += 4) {
    int2 d_e = de[lo + ei];
    const uint4* kp = (const uint4*)(qkv + (size_t)d_e.x * 768 + 256 + h * 16);
    float d = dot8(q0, kp[0]) + dot8(q1, kp[1]);
    exsum += __expf(d + bias[(size_t)d_e.y * HEADS + h]);
  }
  exsum += __shfl_xor(exsum, 16);
  exsum += __shfl_xor(exsum, 32);
  float rden = (exsum > 0.f) ? 1.0f / exsum : 0.f;
  float a0 = 0.f, a1 = 0.f, a2 = 0.f;
  for (int ei = eslot; ei < deg; ei += 4) {
    int2 d_e = de[lo + ei];
    const uint4* kp = (const uint4*)(qkv + (size_t)d_e.x * 768 + 256 + h * 16);
    float d = dot8(q0, kp[0]) + dot8(q1, kp[1]);
    float pr = __expf(d + bias[(size_t)d_e.y * HEADS + h]) * rden;
    const float* vp = vw + (size_t)d_e.x * 48 + h * 3;
    const float* dp = edge_diff + (size_t)d_e.y * 3;
    a0 += pr * vp[0] * dp[0];
    a1 += pr * vp[1] * dp[1];
    a2 += pr * vp[2] * dp[2];
  }
  #pragma unroll
  for (int o = 1; o < 64; o <<= 1) {
    a0 += __shfl_xor(a0, o);
    a1 += __shfl_xor(a1, o);
    a2 += __shfl_xor(a2, o);
  }
  if (lane == 0) {
    out[src * 3 + 0] = a0 + bf1[0];
    out[src * 3 + 1] = a1 + bf2[0];
    out[src * 3 + 2] = a2 + bf3[0];
  }
}

// ------------------------------------------------------------------
extern "C" void kernel_launch(void* const* d_in, const int* in_sizes, int n_in,
                              void* d_out, int out_size, void* d_ws,
                              size_t ws_size, hipStream_t stream) {
  const float* query      = (const float*)d_in[0];
  const int*   edge_index = (const int*)d_in[1];
  const float* edge_diff  = (const float*)d_in[2];
  const float* pair       = (const float*)d_in[3];
  const float* ln_w       = (const float*)d_in[4];
  const float* ln_b       = (const float*)d_in[5];
  const float* pln_w      = (const float*)d_in[6];
  const float* pln_b      = (const float*)d_in[7];
  const float* Wq         = (const float*)d_in[8];
  const float* Wk         = (const float*)d_in[9];
  const float* Wv         = (const float*)d_in[10];
  const float* Wb         = (const float*)d_in[11];
  const float* bb         = (const float*)d_in[12];
  const float* Wf1        = (const float*)d_in[13];
  const float* bf1        = (const float*)d_in[14];
  const float* Wf2        = (const float*)d_in[15];
  const float* bf2        = (const float*)d_in[16];
  const float* Wf3        = (const float*)d_in[17];
  const float* bf3        = (const float*)d_in[18];

  char* ws = (char*)d_ws;
  u16*   qkv   = (u16*)(ws + WS_QKV);
  u16*   qn    = (u16*)(ws + WS_QN);
  u16*   Wbf   = (u16*)(ws + WS_WBF);
  u16*   WWbf  = (u16*)(ws + WS_WW);
  float* c0    = (float*)(ws + WS_C0);
  float* c1    = (float*)(ws + WS_C1);
  float* bias  = (float*)(ws + WS_BIAS);
  float* vw    = (float*)(ws + WS_VW);
  int*   counts= (int*)(ws + WS_CNT);
  int*   cur   = (int*)(ws + WS_CUR);
  int*   off   = (int*)(ws + WS_OFF);
  int2*  de    = (int2*)(ws + WS_DE);
  float* out   = (float*)d_out;

  ln_qn_kernel<<<N_NODE / 4, 256, 0, stream>>>(query, ln_w, ln_b, qn, counts,
                                               cur);
  wcvt_kernel<<<192, 256, 0, stream>>>(Wq, Wk, Wv, Wbf);
  prep_kernel<<<16, 64, 0, stream>>>(pln_w, pln_b, Wb, bb, WWbf, c0, c1);
  dim3 ggrid((N_NODE + 63) / 64, 12);
  qkv_gemm_kernel<<<ggrid, 256, 0, stream>>>(qn, Wbf, qkv);
  vw_kernel<<<1250, 256, 0, stream>>>(qkv, Wf1, Wf2, Wf3, vw);
  pair_bias_kernel<<<N_EDGE / 64, 256, 0, stream>>>(pair, WWbf, c0, c1, bias);
  hist_kernel<<<(N_EDGE + 255) / 256, 256, 0, stream>>>(edge_index, counts);
  scan_kernel<<<1, 1024, 0, stream>>>(counts, off);
  scatter_kernel<<<(N_EDGE + 255) / 256, 256, 0, stream>>>(edge_index, off, cur,
                                                           de);
  seg_attn_kernel<<<N_NODE / 4, 256, 0, stream>>>(qkv, bias, off, de, vw,
                                                  edge_diff, bf1, bf2, bf3,
                                                  out);
}

// Round 5
// 314.034 us; speedup vs baseline: 1.0165x; 1.0165x over previous
//
#include <hip/hip_runtime.h>
#include <math.h>

#define N_NODE 20000
#define N_EDGE 200000
#define EMBED 256
#define PAIR 128
#define HEADS 16
#define HEAD_DIM 16
#define SCALING 0.25f
#define LNEPS 1e-5f

typedef unsigned short u16;
typedef unsigned int u32;
typedef __attribute__((ext_vector_type(8))) short bf16x8;
typedef __attribute__((ext_vector_type(4))) float f32x4;

// ---------------- workspace layout (bytes) ----------------
#define WS_QKV   0            // qkv_bf : 20000*768*2  = 30,720,000 (q scaled)
#define WS_QN    30720000     // qn_bf  : 20000*256*2  = 10,240,000
#define WS_WBF   40960000     // Wbf    : 768*256*2    =    393,216
#define WS_WW    41353216     // WW_bf  : 16*128*2     =      4,096
#define WS_C0    41357312     // c0     : 16*4 (pad 64)
#define WS_C1    41357376     // c1     : 16*4 (pad 64)
#define WS_BIAS  41357440     // bias   : 200000*16*4  = 12,800,000
#define WS_VW    54157440     // vw     : 20000*48*4   =  3,840,000
#define WS_CNT   57997440     // counts : 20000*4
#define WS_CUR   58077440     // cursor : 20000*4
#define WS_OFF   58157440     // off    : 20001*4 (pad to 80064)
#define WS_DE    58237504     // {dst,e}: 200000*8     =  1,600,000

__device__ __forceinline__ u16 f2bf(float f) {
  u32 u = __float_as_uint(f);
  u32 r = (u + 0x7FFFu + ((u >> 16) & 1u)) >> 16;
  return (u16)r;
}
__device__ __forceinline__ float bl(u32 u) { return __uint_as_float(u << 16); }
__device__ __forceinline__ float bh(u32 u) { return __uint_as_float(u & 0xFFFF0000u); }

__device__ __forceinline__ float dot8(uint4 a, uint4 b) {
  float s = bl(a.x) * bl(b.x) + bh(a.x) * bh(b.x);
  s += bl(a.y) * bl(b.y) + bh(a.y) * bh(b.y);
  s += bl(a.z) * bl(b.z) + bh(a.z) * bh(b.z);
  s += bl(a.w) * bl(b.w) + bh(a.w) * bh(b.w);
  return s;
}

// ------------------------------------------------------------------
// K1: per-node LN -> qn_bf. One wave per node. Also zeroes CSR counters.
__global__ __launch_bounds__(256) void ln_qn_kernel(
    const float* __restrict__ query, const float* __restrict__ ln_w,
    const float* __restrict__ ln_b, u16* __restrict__ qn,
    int* __restrict__ counts, int* __restrict__ cur) {
  int z = blockIdx.x * 256 + threadIdx.x;
  if (z < N_NODE) { counts[z] = 0; cur[z] = 0; }
  int node = blockIdx.x * 4 + (threadIdx.x >> 6);
  int lane = threadIdx.x & 63;
  float4 a = *(const float4*)(query + (size_t)node * EMBED + lane * 4);
  float s = a.x + a.y + a.z + a.w;
  float s2 = a.x * a.x + a.y * a.y + a.z * a.z + a.w * a.w;
  #pragma unroll
  for (int off = 32; off > 0; off >>= 1) {
    s += __shfl_xor(s, off);
    s2 += __shfl_xor(s2, off);
  }
  float m = s * (1.0f / EMBED);
  float r = rsqrtf(s2 * (1.0f / EMBED) - m * m + LNEPS);
  float4 w4 = *(const float4*)(ln_w + lane * 4);
  float4 b4 = *(const float4*)(ln_b + lane * 4);
  ushort4 st;
  st.x = f2bf((a.x - m) * r * w4.x + b4.x);
  st.y = f2bf((a.y - m) * r * w4.y + b4.y);
  st.z = f2bf((a.z - m) * r * w4.z + b4.z);
  st.w = f2bf((a.w - m) * r * w4.w + b4.w);
  *(ushort4*)(qn + (size_t)node * EMBED + lane * 4) = st;
}

// ------------------------------------------------------------------
// K2: merged — blocks 0..191: Wq|Wk|Wv -> Wbf bf16. Block 192 (1 wave used):
// WW_bf[h][i]=bf16(plw[i]*Wb[h][i]); c1[h]=sum WW; c0[h]=sum plb*Wb + bb.
__global__ __launch_bounds__(256) void wcvt_prep_kernel(
    const float* __restrict__ Wq, const float* __restrict__ Wk,
    const float* __restrict__ Wv, u16* __restrict__ Wbf,
    const float* __restrict__ pln_w, const float* __restrict__ pln_b,
    const float* __restrict__ Wb, const float* __restrict__ bb,
    u16* __restrict__ WWbf, float* __restrict__ c0, float* __restrict__ c1) {
  if (blockIdx.x < 192) {
    int g4 = blockIdx.x * 256 + threadIdx.x;
    int idx = g4 * 4;
    const float* src = (idx < 65536) ? Wq : (idx < 131072 ? Wk : Wv);
    float4 v = *(const float4*)(src + (idx & 65535));
    ushort4 st = {f2bf(v.x), f2bf(v.y), f2bf(v.z), f2bf(v.w)};
    *(ushort4*)(Wbf + idx) = st;
  } else if (threadIdx.x < 64) {
    int l = threadIdx.x;
    for (int h = 0; h < HEADS; h++) {
      int i0 = l * 2;
      float wb0 = Wb[h * PAIR + i0], wb1 = Wb[h * PAIR + i0 + 1];
      float ww0 = pln_w[i0] * wb0, ww1 = pln_w[i0 + 1] * wb1;
      WWbf[h * PAIR + i0] = f2bf(ww0);
      WWbf[h * PAIR + i0 + 1] = f2bf(ww1);
      float s1 = ww0 + ww1;
      float s0 = pln_b[i0] * wb0 + pln_b[i0 + 1] * wb1;
      #pragma unroll
      for (int off = 32; off > 0; off >>= 1) {
        s1 += __shfl_xor(s1, off);
        s0 += __shfl_xor(s0, off);
      }
      if (l == 0) {
        c1[h] = s1;
        c0[h] = s0 + bb[h];
      }
    }
  }
}

// ------------------------------------------------------------------
// K3: bf16 MFMA GEMM (R2-proven): qkv[n][j] = qn[n].Wbf[j], j in 0..767.
// 64x64 tile, full K=256 staged once. LDS rows padded to 264 ushorts.
#define GP 264
__global__ __launch_bounds__(256, 2) void qkv_gemm_kernel(
    const u16* __restrict__ qn, const u16* __restrict__ Wbf,
    u16* __restrict__ qkv) {
  __shared__ u16 As[64 * GP];
  __shared__ u16 Bs[64 * GP];
  int t = threadIdx.x;
  int wv = t >> 6, lane = t & 63;
  int quad = lane >> 4, l16 = lane & 15;
  int row0 = blockIdx.x * 64, col0 = blockIdx.y * 64;
  #pragma unroll
  for (int j = 0; j < 8; j++) {
    int row = j * 8 + (t >> 5);
    int slot = t & 31;
    int ra = min(row0 + row, N_NODE - 1);
    uint4 va = *(const uint4*)(qn + (size_t)ra * 256 + slot * 8);
    *(uint4*)(&As[row * GP + slot * 8]) = va;
    uint4 vb = *(const uint4*)(Wbf + (size_t)(col0 + row) * 256 + slot * 8);
    *(uint4*)(&Bs[row * GP + slot * 8]) = vb;
  }
  __syncthreads();
  int mt = (wv >> 1) * 32, nt = (wv & 1) * 32;
  f32x4 acc[2][2];
  #pragma unroll
  for (int im = 0; im < 2; im++)
    #pragma unroll
    for (int in_ = 0; in_ < 2; in_++) acc[im][in_] = (f32x4){0.f, 0.f, 0.f, 0.f};
  #pragma unroll
  for (int sk = 0; sk < 8; sk++) {
    int ko = sk * 32 + quad * 8;
    bf16x8 a0 = *(const bf16x8*)(&As[(mt + l16) * GP + ko]);
    bf16x8 a1 = *(const bf16x8*)(&As[(mt + 16 + l16) * GP + ko]);
    bf16x8 b0 = *(const bf16x8*)(&Bs[(nt + l16) * GP + ko]);
    bf16x8 b1 = *(const bf16x8*)(&Bs[(nt + 16 + l16) * GP + ko]);
    acc[0][0] = __builtin_amdgcn_mfma_f32_16x16x32_bf16(a0, b0, acc[0][0], 0, 0, 0);
    acc[0][1] = __builtin_amdgcn_mfma_f32_16x16x32_bf16(a0, b1, acc[0][1], 0, 0, 0);
    acc[1][0] = __builtin_amdgcn_mfma_f32_16x16x32_bf16(a1, b0, acc[1][0], 0, 0, 0);
    acc[1][1] = __builtin_amdgcn_mfma_f32_16x16x32_bf16(a1, b1, acc[1][1], 0, 0, 0);
  }
  float scale = (col0 < 256) ? SCALING : 1.0f;
  #pragma unroll
  for (int im = 0; im < 2; im++) {
    #pragma unroll
    for (int in_ = 0; in_ < 2; in_++) {
      #pragma unroll
      for (int r = 0; r < 4; r++) {
        int grow = row0 + mt + im * 16 + quad * 4 + r;
        int gcol = col0 + nt + in_ * 16 + l16;
        if (grow < N_NODE)
          qkv[(size_t)grow * 768 + gcol] = f2bf(acc[im][in_][r] * scale);
      }
    }
  }
}

// ------------------------------------------------------------------
// K4: vw[n][h][c] = sum_d v[n,h*16+d]*Wf_c[h*16+d] (R2-proven).
__global__ __launch_bounds__(256) void vw_kernel(
    const u16* __restrict__ qkv, const float* __restrict__ Wf1,
    const float* __restrict__ Wf2, const float* __restrict__ Wf3,
    float* __restrict__ vw) {
  int gid = blockIdx.x * 256 + threadIdx.x;  // 320000
  int n = gid >> 4, h = gid & 15;
  const uint4* vp = (const uint4*)(qkv + (size_t)n * 768 + 512 + h * 16);
  uint4 va = vp[0], vb = vp[1];
  float v[16];
  v[0] = bl(va.x); v[1] = bh(va.x); v[2] = bl(va.y); v[3] = bh(va.y);
  v[4] = bl(va.z); v[5] = bh(va.z); v[6] = bl(va.w); v[7] = bh(va.w);
  v[8] = bl(vb.x); v[9] = bh(vb.x); v[10] = bl(vb.y); v[11] = bh(vb.y);
  v[12] = bl(vb.z); v[13] = bh(vb.z); v[14] = bl(vb.w); v[15] = bh(vb.w);
  const float* wf[3] = {Wf1 + h * 16, Wf2 + h * 16, Wf3 + h * 16};
  #pragma unroll
  for (int c = 0; c < 3; c++) {
    float s = 0.f;
    #pragma unroll
    for (int d = 0; d < 16; d++) s += v[d] * wf[c][d];
    vw[(size_t)n * 48 + h * 3 + c] = s;
  }
}

// ------------------------------------------------------------------
// K5: pair bias via MFMA (R2-proven): bias[e][h] = r_e*(p.WW_h - m_e*c1_h)+c0_h.
#define PP 136
__global__ __launch_bounds__(256) void pair_bias_kernel(
    const float* __restrict__ pair, const u16* __restrict__ WWbf,
    const float* __restrict__ c0g, const float* __restrict__ c1g,
    float* __restrict__ bias) {
  __shared__ u16 Ps[64 * PP];
  __shared__ u16 WWs[16 * PP];
  __shared__ float ms[64], rs[64], c0s[16], c1s[16];
  int t = threadIdx.x;
  int wv = t >> 6, lane = t & 63;
  int quad = lane >> 4, l16 = lane & 15;
  int e0 = blockIdx.x * 64;
  #pragma unroll
  for (int j = 0; j < 8; j++) {
    int L = j * 256 + t;
    int row = L >> 5, slot = L & 31;
    float4 p = *(const float4*)(pair + (size_t)(e0 + row) * PAIR + slot * 4);
    ushort4 st = {f2bf(p.x), f2bf(p.y), f2bf(p.z), f2bf(p.w)};
    *(ushort4*)(&Ps[row * PP + slot * 4]) = st;
  }
  #pragma unroll
  for (int j = 0; j < 2; j++) {
    int L = j * 256 + t;
    int row = L >> 5, slot = L & 31;
    ushort4 w = *(const ushort4*)(WWbf + row * PAIR + slot * 4);
    *(ushort4*)(&WWs[row * PP + slot * 4]) = w;
  }
  if (t < 16) {
    c0s[t] = c0g[t];
    c1s[t] = c1g[t];
  }
  __syncthreads();
  {
    int row = t >> 2, qq = t & 3;
    float s = 0.f, s2 = 0.f;
    #pragma unroll
    for (int jj = 0; jj < 8; jj++) {
      ushort4 u = *(const ushort4*)(&Ps[row * PP + (qq * 8 + jj) * 4]);
      float x0 = __uint_as_float((u32)u.x << 16);
      float x1 = __uint_as_float((u32)u.y << 16);
      float x2 = __uint_as_float((u32)u.z << 16);
      float x3 = __uint_as_float((u32)u.w << 16);
      s += x0 + x1 + x2 + x3;
      s2 += x0 * x0 + x1 * x1 + x2 * x2 + x3 * x3;
    }
    s += __shfl_xor(s, 1); s += __shfl_xor(s, 2);
    s2 += __shfl_xor(s2, 1); s2 += __shfl_xor(s2, 2);
    if (qq == 0) {
      float m = s * (1.0f / PAIR);
      ms[row] = m;
      rs[row] = rsqrtf(s2 * (1.0f / PAIR) - m * m + LNEPS);
    }
  }
  __syncthreads();
  f32x4 acc = (f32x4){0.f, 0.f, 0.f, 0.f};
  #pragma unroll
  for (int sk = 0; sk < 4; sk++) {
    int ko = sk * 32 + quad * 8;
    bf16x8 a = *(const bf16x8*)(&Ps[(wv * 16 + l16) * PP + ko]);
    bf16x8 b = *(const bf16x8*)(&WWs[l16 * PP + ko]);
    acc = __builtin_amdgcn_mfma_f32_16x16x32_bf16(a, b, acc, 0, 0, 0);
  }
  #pragma unroll
  for (int r = 0; r < 4; r++) {
    int el = wv * 16 + quad * 4 + r;
    float bv = rs[el] * (acc[r] - ms[el] * c1s[l16]) + c0s[l16];
    bias[(size_t)(e0 + el) * HEADS + l16] = bv;
  }
}

// ------------------------------------------------------------------
// K6: histogram of src.
__global__ __launch_bounds__(256) void hist_kernel(
    const int* __restrict__ edge_index, int* __restrict__ counts) {
  int e = blockIdx.x * 256 + threadIdx.x;
  if (e < N_EDGE) atomicAdd(&counts[edge_index[e * 2]], 1);
}

// ------------------------------------------------------------------
// K7: exclusive scan of counts (20000) -> off[0..20000]. Single block.
__global__ __launch_bounds__(1024) void scan_kernel(
    const int* __restrict__ counts, int* __restrict__ off) {
  __shared__ int part[1024];
  int t = threadIdx.x;
  int loc[20];
  int s = 0;
  #pragma unroll
  for (int i = 0; i < 20; i++) {
    int idx = t * 20 + i;
    int v = (idx < N_NODE) ? counts[idx] : 0;
    loc[i] = s;
    s += v;
  }
  part[t] = s;
  __syncthreads();
  int x = s;
  for (int o = 1; o < 1024; o <<= 1) {
    int y = (t >= o) ? part[t - o] : 0;
    __syncthreads();
    x += y;
    part[t] = x;
    __syncthreads();
  }
  int excl = x - s;
  #pragma unroll
  for (int i = 0; i < 20; i++) {
    int idx = t * 20 + i;
    if (idx < N_NODE) off[idx] = excl + loc[i];
  }
  if (t == 0) off[N_NODE] = N_EDGE;
}

// ------------------------------------------------------------------
// K8: scatter edges into CSR order: de[pos] = {dst, e}.
__global__ __launch_bounds__(256) void scatter_kernel(
    const int* __restrict__ edge_index, const int* __restrict__ off,
    int* __restrict__ cur, int2* __restrict__ de) {
  int e = blockIdx.x * 256 + threadIdx.x;
  if (e >= N_EDGE) return;
  int src = edge_index[e * 2 + 0];
  int dst = edge_index[e * 2 + 1];
  int pos = off[src] + atomicAdd(&cur[src], 1);
  de[pos] = make_int2(dst, e);
}

// ------------------------------------------------------------------
// K9: segmented attention, SINGLE PASS. One wave per src node; lane=(h,eslot).
// Accumulate unnormalized num_c = sum ex*vw_c*diff_c and exsum per lane; the
// per-(src,h) 1/denom is applied after the cross-eslot reduction (division
// distributes over the sum), then a full 64-lane butterfly folds h+eslot.
// Plain store — no atomics, no LDS, no second gather.
__global__ __launch_bounds__(256) void seg_attn_kernel(
    const u16* __restrict__ qkv, const float* __restrict__ bias,
    const int* __restrict__ off, const int2* __restrict__ de,
    const float* __restrict__ vw, const float* __restrict__ edge_diff,
    const float* __restrict__ bf1, const float* __restrict__ bf2,
    const float* __restrict__ bf3, float* __restrict__ out) {
  int wv = threadIdx.x >> 6, lane = threadIdx.x & 63;
  int src = blockIdx.x * 4 + wv;
  int h = lane & 15, eslot = lane >> 4;
  int lo = off[src];
  int deg = off[src + 1] - lo;
  const uint4* qp = (const uint4*)(qkv + (size_t)src * 768 + h * 16);
  uint4 q0 = qp[0], q1 = qp[1];
  float exsum = 0.f, a0 = 0.f, a1 = 0.f, a2 = 0.f;
  for (int ei = eslot; ei < deg; ei += 4) {
    int2 d_e = de[lo + ei];
    const uint4* kp = (const uint4*)(qkv + (size_t)d_e.x * 768 + 256 + h * 16);
    float d = dot8(q0, kp[0]) + dot8(q1, kp[1]);
    float ex = __expf(d + bias[(size_t)d_e.y * HEADS + h]);
    exsum += ex;
    const float* vp = vw + (size_t)d_e.x * 48 + h * 3;
    const float* dp = edge_diff + (size_t)d_e.y * 3;
    a0 += ex * vp[0] * dp[0];
    a1 += ex * vp[1] * dp[1];
    a2 += ex * vp[2] * dp[2];
  }
  // per-(src,h) denom: reduce across the 4 eslots (lanes h, h+16, h+32, h+48)
  exsum += __shfl_xor(exsum, 16);
  exsum += __shfl_xor(exsum, 32);
  float rden = (exsum > 0.f) ? 1.0f / exsum : 0.f;
  a0 *= rden; a1 *= rden; a2 *= rden;
  #pragma unroll
  for (int o = 1; o < 64; o <<= 1) {
    a0 += __shfl_xor(a0, o);
    a1 += __shfl_xor(a1, o);
    a2 += __shfl_xor(a2, o);
  }
  if (lane == 0) {
    out[src * 3 + 0] = a0 + bf1[0];
    out[src * 3 + 1] = a1 + bf2[0];
    out[src * 3 + 2] = a2 + bf3[0];
  }
}

// ------------------------------------------------------------------
extern "C" void kernel_launch(void* const* d_in, const int* in_sizes, int n_in,
                              void* d_out, int out_size, void* d_ws,
                              size_t ws_size, hipStream_t stream) {
  const float* query      = (const float*)d_in[0];
  const int*   edge_index = (const int*)d_in[1];
  const float* edge_diff  = (const float*)d_in[2];
  const float* pair       = (const float*)d_in[3];
  const float* ln_w       = (const float*)d_in[4];
  const float* ln_b       = (const float*)d_in[5];
  const float* pln_w      = (const float*)d_in[6];
  const float* pln_b      = (const float*)d_in[7];
  const float* Wq         = (const float*)d_in[8];
  const float* Wk         = (const float*)d_in[9];
  const float* Wv         = (const float*)d_in[10];
  const float* Wb         = (const float*)d_in[11];
  const float* bb         = (const float*)d_in[12];
  const float* Wf1        = (const float*)d_in[13];
  const float* bf1        = (const float*)d_in[14];
  const float* Wf2        = (const float*)d_in[15];
  const float* bf2        = (const float*)d_in[16];
  const float* Wf3        = (const float*)d_in[17];
  const float* bf3        = (const float*)d_in[18];

  char* ws = (char*)d_ws;
  u16*   qkv   = (u16*)(ws + WS_QKV);
  u16*   qn    = (u16*)(ws + WS_QN);
  u16*   Wbf   = (u16*)(ws + WS_WBF);
  u16*   WWbf  = (u16*)(ws + WS_WW);
  float* c0    = (float*)(ws + WS_C0);
  float* c1    = (float*)(ws + WS_C1);
  float* bias  = (float*)(ws + WS_BIAS);
  float* vw    = (float*)(ws + WS_VW);
  int*   counts= (int*)(ws + WS_CNT);
  int*   cur   = (int*)(ws + WS_CUR);
  int*   off   = (int*)(ws + WS_OFF);
  int2*  de    = (int2*)(ws + WS_DE);
  float* out   = (float*)d_out;

  ln_qn_kernel<<<N_NODE / 4, 256, 0, stream>>>(query, ln_w, ln_b, qn, counts,
                                               cur);
  wcvt_prep_kernel<<<193, 256, 0, stream>>>(Wq, Wk, Wv, Wbf, pln_w, pln_b, Wb,
                                            bb, WWbf, c0, c1);
  dim3 ggrid((N_NODE + 63) / 64, 12);
  qkv_gemm_kernel<<<ggrid, 256, 0, stream>>>(qn, Wbf, qkv);
  vw_kernel<<<1250, 256, 0, stream>>>(qkv, Wf1, Wf2, Wf3, vw);
  pair_bias_kernel<<<N_EDGE / 64, 256, 0, stream>>>(pair, WWbf, c0, c1, bias);
  hist_kernel<<<(N_EDGE + 255) / 256, 256, 0, stream>>>(edge_index, counts);
  scan_kernel<<<1, 1024, 0, stream>>>(counts, off);
  scatter_kernel<<<(N_EDGE + 255) / 256, 256, 0, stream>>>(edge_index, off, cur,
                                                           de);
  seg_attn_kernel<<<N_NODE / 4, 256, 0, stream>>>(qkv, bias, off, de, vw,
                                                  edge_diff, bf1, bf2, bf3,
                                                  out);
}

// Round 6
// 295.830 us; speedup vs baseline: 1.0790x; 1.0615x over previous
//
#include <hip/hip_runtime.h>
#include <math.h>

#define N_NODE 20000
#define N_EDGE 200000
#define EMBED 256
#define PAIR 128
#define HEADS 16
#define HEAD_DIM 16
#define SCALING 0.25f
#define LNEPS 1e-5f

typedef unsigned short u16;
typedef unsigned int u32;
typedef __attribute__((ext_vector_type(8))) short bf16x8;
typedef __attribute__((ext_vector_type(4))) float f32x4;

// ---------------- workspace layout (bytes) ----------------
#define WS_QKV   0            // qkv_bf : 20000*768*2  = 30,720,000 (q scaled)
#define WS_QN    30720000     // qn_bf  : 20000*256*2  = 10,240,000
#define WS_WBF   40960000     // Wbf    : 768*256*2    =    393,216
#define WS_WW    41353216     // WW_bf  : 16*128*2     =      4,096
#define WS_C0    41357312     // c0     : 16*4 (pad 64)
#define WS_C1    41357376     // c1     : 16*4 (pad 64)
#define WS_BIAS  41357440     // bias   : 200000*16*4  = 12,800,000
#define WS_VW    54157440     // vw     : 20000*48*4   =  3,840,000
#define WS_CNT   57997440     // counts : 20000*4
#define WS_CUR   58077440     // cursor : 20000*4
#define WS_OFF   58157440     // off    : 20001*4 (pad to 80064)
#define WS_DE    58237504     // {dst,e}: 200000*8     =  1,600,000

__device__ __forceinline__ u16 f2bf(float f) {
  u32 u = __float_as_uint(f);
  u32 r = (u + 0x7FFFu + ((u >> 16) & 1u)) >> 16;
  return (u16)r;
}
__device__ __forceinline__ float bl(u32 u) { return __uint_as_float(u << 16); }
__device__ __forceinline__ float bh(u32 u) { return __uint_as_float(u & 0xFFFF0000u); }

__device__ __forceinline__ float dot8(uint4 a, uint4 b) {
  float s = bl(a.x) * bl(b.x) + bh(a.x) * bh(b.x);
  s += bl(a.y) * bl(b.y) + bh(a.y) * bh(b.y);
  s += bl(a.z) * bl(b.z) + bh(a.z) * bh(b.z);
  s += bl(a.w) * bl(b.w) + bh(a.w) * bh(b.w);
  return s;
}

// ==================================================================
// K1: block-partitioned — [0,5000): ln_qn (+zero counts/cur);
// [5000,5192): wcvt; 5192: prep.
__global__ __launch_bounds__(256) void k1_pre_kernel(
    const float* __restrict__ query, const float* __restrict__ ln_w,
    const float* __restrict__ ln_b, u16* __restrict__ qn,
    int* __restrict__ counts, int* __restrict__ cur,
    const float* __restrict__ Wq, const float* __restrict__ Wk,
    const float* __restrict__ Wv, u16* __restrict__ Wbf,
    const float* __restrict__ pln_w, const float* __restrict__ pln_b,
    const float* __restrict__ Wb, const float* __restrict__ bb,
    u16* __restrict__ WWbf, float* __restrict__ c0, float* __restrict__ c1) {
  int bid = blockIdx.x;
  if (bid < 5000) {
    int z = bid * 256 + threadIdx.x;
    if (z < N_NODE) { counts[z] = 0; cur[z] = 0; }
    int node = bid * 4 + (threadIdx.x >> 6);
    int lane = threadIdx.x & 63;
    float4 a = *(const float4*)(query + (size_t)node * EMBED + lane * 4);
    float s = a.x + a.y + a.z + a.w;
    float s2 = a.x * a.x + a.y * a.y + a.z * a.z + a.w * a.w;
    #pragma unroll
    for (int off = 32; off > 0; off >>= 1) {
      s += __shfl_xor(s, off);
      s2 += __shfl_xor(s2, off);
    }
    float m = s * (1.0f / EMBED);
    float r = rsqrtf(s2 * (1.0f / EMBED) - m * m + LNEPS);
    float4 w4 = *(const float4*)(ln_w + lane * 4);
    float4 b4 = *(const float4*)(ln_b + lane * 4);
    ushort4 st;
    st.x = f2bf((a.x - m) * r * w4.x + b4.x);
    st.y = f2bf((a.y - m) * r * w4.y + b4.y);
    st.z = f2bf((a.z - m) * r * w4.z + b4.z);
    st.w = f2bf((a.w - m) * r * w4.w + b4.w);
    *(ushort4*)(qn + (size_t)node * EMBED + lane * 4) = st;
  } else if (bid < 5192) {
    int g4 = (bid - 5000) * 256 + threadIdx.x;
    int idx = g4 * 4;
    const float* src = (idx < 65536) ? Wq : (idx < 131072 ? Wk : Wv);
    float4 v = *(const float4*)(src + (idx & 65535));
    ushort4 st = {f2bf(v.x), f2bf(v.y), f2bf(v.z), f2bf(v.w)};
    *(ushort4*)(Wbf + idx) = st;
  } else if (threadIdx.x < 64) {
    int l = threadIdx.x;
    for (int h = 0; h < HEADS; h++) {
      int i0 = l * 2;
      float wb0 = Wb[h * PAIR + i0], wb1 = Wb[h * PAIR + i0 + 1];
      float ww0 = pln_w[i0] * wb0, ww1 = pln_w[i0 + 1] * wb1;
      WWbf[h * PAIR + i0] = f2bf(ww0);
      WWbf[h * PAIR + i0 + 1] = f2bf(ww1);
      float s1 = ww0 + ww1;
      float s0 = pln_b[i0] * wb0 + pln_b[i0 + 1] * wb1;
      #pragma unroll
      for (int off = 32; off > 0; off >>= 1) {
        s1 += __shfl_xor(s1, off);
        s0 += __shfl_xor(s0, off);
      }
      if (l == 0) {
        c1[h] = s1;
        c0[h] = s0 + bb[h];
      }
    }
  }
}

// ==================================================================
// K2: block-partitioned — [0,3756): qkv GEMM (R2-proven inner code);
// [3756,4538): hist.
#define GP 264
__global__ __launch_bounds__(256, 2) void k2_gemm_hist_kernel(
    const u16* __restrict__ qn, const u16* __restrict__ Wbf,
    u16* __restrict__ qkv, const int* __restrict__ edge_index,
    int* __restrict__ counts) {
  __shared__ u16 As[64 * GP];
  __shared__ u16 Bs[64 * GP];
  int bid = blockIdx.x;
  if (bid >= 3756) {
    int e = (bid - 3756) * 256 + threadIdx.x;
    if (e < N_EDGE) atomicAdd(&counts[edge_index[e * 2]], 1);
    return;
  }
  int bx = bid % 313, by = bid / 313;
  int t = threadIdx.x;
  int wv = t >> 6, lane = t & 63;
  int quad = lane >> 4, l16 = lane & 15;
  int row0 = bx * 64, col0 = by * 64;
  #pragma unroll
  for (int j = 0; j < 8; j++) {
    int row = j * 8 + (t >> 5);
    int slot = t & 31;
    int ra = min(row0 + row, N_NODE - 1);
    uint4 va = *(const uint4*)(qn + (size_t)ra * 256 + slot * 8);
    *(uint4*)(&As[row * GP + slot * 8]) = va;
    uint4 vb = *(const uint4*)(Wbf + (size_t)(col0 + row) * 256 + slot * 8);
    *(uint4*)(&Bs[row * GP + slot * 8]) = vb;
  }
  __syncthreads();
  int mt = (wv >> 1) * 32, nt = (wv & 1) * 32;
  f32x4 acc[2][2];
  #pragma unroll
  for (int im = 0; im < 2; im++)
    #pragma unroll
    for (int in_ = 0; in_ < 2; in_++) acc[im][in_] = (f32x4){0.f, 0.f, 0.f, 0.f};
  #pragma unroll
  for (int sk = 0; sk < 8; sk++) {
    int ko = sk * 32 + quad * 8;
    bf16x8 a0 = *(const bf16x8*)(&As[(mt + l16) * GP + ko]);
    bf16x8 a1 = *(const bf16x8*)(&As[(mt + 16 + l16) * GP + ko]);
    bf16x8 b0 = *(const bf16x8*)(&Bs[(nt + l16) * GP + ko]);
    bf16x8 b1 = *(const bf16x8*)(&Bs[(nt + 16 + l16) * GP + ko]);
    acc[0][0] = __builtin_amdgcn_mfma_f32_16x16x32_bf16(a0, b0, acc[0][0], 0, 0, 0);
    acc[0][1] = __builtin_amdgcn_mfma_f32_16x16x32_bf16(a0, b1, acc[0][1], 0, 0, 0);
    acc[1][0] = __builtin_amdgcn_mfma_f32_16x16x32_bf16(a1, b0, acc[1][0], 0, 0, 0);
    acc[1][1] = __builtin_amdgcn_mfma_f32_16x16x32_bf16(a1, b1, acc[1][1], 0, 0, 0);
  }
  float scale = (col0 < 256) ? SCALING : 1.0f;
  #pragma unroll
  for (int im = 0; im < 2; im++) {
    #pragma unroll
    for (int in_ = 0; in_ < 2; in_++) {
      #pragma unroll
      for (int r = 0; r < 4; r++) {
        int grow = row0 + mt + im * 16 + quad * 4 + r;
        int gcol = col0 + nt + in_ * 16 + l16;
        if (grow < N_NODE)
          qkv[(size_t)grow * 768 + gcol] = f2bf(acc[im][in_][r] * scale);
      }
    }
  }
}

// ==================================================================
// K3: exclusive scan of counts (20000) -> off[0..20000]. Single block.
__global__ __launch_bounds__(1024) void scan_kernel(
    const int* __restrict__ counts, int* __restrict__ off) {
  __shared__ int part[1024];
  int t = threadIdx.x;
  int loc[20];
  int s = 0;
  #pragma unroll
  for (int i = 0; i < 20; i++) {
    int idx = t * 20 + i;
    int v = (idx < N_NODE) ? counts[idx] : 0;
    loc[i] = s;
    s += v;
  }
  part[t] = s;
  __syncthreads();
  int x = s;
  for (int o = 1; o < 1024; o <<= 1) {
    int y = (t >= o) ? part[t - o] : 0;
    __syncthreads();
    x += y;
    part[t] = x;
    __syncthreads();
  }
  int excl = x - s;
  #pragma unroll
  for (int i = 0; i < 20; i++) {
    int idx = t * 20 + i;
    if (idx < N_NODE) off[idx] = excl + loc[i];
  }
  if (t == 0) off[N_NODE] = N_EDGE;
}

// ==================================================================
// K4: block-partitioned — [0,3125): pair_bias (R2-proven);
// [3125,4375): vw (R2-proven); [4375,5157): scatter.
#define PP 136
__global__ __launch_bounds__(256) void k4_bias_vw_scatter_kernel(
    const float* __restrict__ pair, const u16* __restrict__ WWbf,
    const float* __restrict__ c0g, const float* __restrict__ c1g,
    float* __restrict__ bias, const u16* __restrict__ qkv,
    const float* __restrict__ Wf1, const float* __restrict__ Wf2,
    const float* __restrict__ Wf3, float* __restrict__ vw,
    const int* __restrict__ edge_index, const int* __restrict__ off,
    int* __restrict__ cur, int2* __restrict__ de) {
  __shared__ u16 Ps[64 * PP];
  __shared__ u16 WWs[16 * PP];
  __shared__ float ms[64], rs[64], c0s[16], c1s[16];
  int bid = blockIdx.x;
  int t = threadIdx.x;
  if (bid >= 4375) {
    int e = (bid - 4375) * 256 + t;
    if (e < N_EDGE) {
      int src = edge_index[e * 2 + 0];
      int dst = edge_index[e * 2 + 1];
      int pos = off[src] + atomicAdd(&cur[src], 1);
      de[pos] = make_int2(dst, e);
    }
    return;
  }
  if (bid >= 3125) {
    int gid = (bid - 3125) * 256 + t;  // 320000
    int n = gid >> 4, h = gid & 15;
    const uint4* vp = (const uint4*)(qkv + (size_t)n * 768 + 512 + h * 16);
    uint4 va = vp[0], vb = vp[1];
    float v[16];
    v[0] = bl(va.x); v[1] = bh(va.x); v[2] = bl(va.y); v[3] = bh(va.y);
    v[4] = bl(va.z); v[5] = bh(va.z); v[6] = bl(va.w); v[7] = bh(va.w);
    v[8] = bl(vb.x); v[9] = bh(vb.x); v[10] = bl(vb.y); v[11] = bh(vb.y);
    v[12] = bl(vb.z); v[13] = bh(vb.z); v[14] = bl(vb.w); v[15] = bh(vb.w);
    const float* wf[3] = {Wf1 + h * 16, Wf2 + h * 16, Wf3 + h * 16};
    #pragma unroll
    for (int c = 0; c < 3; c++) {
      float s = 0.f;
      #pragma unroll
      for (int d = 0; d < 16; d++) s += v[d] * wf[c][d];
      vw[(size_t)n * 48 + h * 3 + c] = s;
    }
    return;
  }
  // ---- pair_bias ----
  int wv = t >> 6, lane = t & 63;
  int quad = lane >> 4, l16 = lane & 15;
  int e0 = bid * 64;
  #pragma unroll
  for (int j = 0; j < 8; j++) {
    int L = j * 256 + t;
    int row = L >> 5, slot = L & 31;
    float4 p = *(const float4*)(pair + (size_t)(e0 + row) * PAIR + slot * 4);
    ushort4 st = {f2bf(p.x), f2bf(p.y), f2bf(p.z), f2bf(p.w)};
    *(ushort4*)(&Ps[row * PP + slot * 4]) = st;
  }
  #pragma unroll
  for (int j = 0; j < 2; j++) {
    int L = j * 256 + t;
    int row = L >> 5, slot = L & 31;
    ushort4 w = *(const ushort4*)(WWbf + row * PAIR + slot * 4);
    *(ushort4*)(&WWs[row * PP + slot * 4]) = w;
  }
  if (t < 16) {
    c0s[t] = c0g[t];
    c1s[t] = c1g[t];
  }
  __syncthreads();
  {
    int row = t >> 2, qq = t & 3;
    float s = 0.f, s2 = 0.f;
    #pragma unroll
    for (int jj = 0; jj < 8; jj++) {
      ushort4 u = *(const ushort4*)(&Ps[row * PP + (qq * 8 + jj) * 4]);
      float x0 = __uint_as_float((u32)u.x << 16);
      float x1 = __uint_as_float((u32)u.y << 16);
      float x2 = __uint_as_float((u32)u.z << 16);
      float x3 = __uint_as_float((u32)u.w << 16);
      s += x0 + x1 + x2 + x3;
      s2 += x0 * x0 + x1 * x1 + x2 * x2 + x3 * x3;
    }
    s += __shfl_xor(s, 1); s += __shfl_xor(s, 2);
    s2 += __shfl_xor(s2, 1); s2 += __shfl_xor(s2, 2);
    if (qq == 0) {
      float m = s * (1.0f / PAIR);
      ms[row] = m;
      rs[row] = rsqrtf(s2 * (1.0f / PAIR) - m * m + LNEPS);
    }
  }
  __syncthreads();
  f32x4 acc = (f32x4){0.f, 0.f, 0.f, 0.f};
  #pragma unroll
  for (int sk = 0; sk < 4; sk++) {
    int ko = sk * 32 + quad * 8;
    bf16x8 a = *(const bf16x8*)(&Ps[(wv * 16 + l16) * PP + ko]);
    bf16x8 b = *(const bf16x8*)(&WWs[l16 * PP + ko]);
    acc = __builtin_amdgcn_mfma_f32_16x16x32_bf16(a, b, acc, 0, 0, 0);
  }
  #pragma unroll
  for (int r = 0; r < 4; r++) {
    int el = wv * 16 + quad * 4 + r;
    float bv = rs[el] * (acc[r] - ms[el] * c1s[l16]) + c0s[l16];
    bias[(size_t)(e0 + el) * HEADS + l16] = bv;
  }
}

// ==================================================================
// K5: segmented attention, single pass (R5-proven).
__global__ __launch_bounds__(256) void seg_attn_kernel(
    const u16* __restrict__ qkv, const float* __restrict__ bias,
    const int* __restrict__ off, const int2* __restrict__ de,
    const float* __restrict__ vw, const float* __restrict__ edge_diff,
    const float* __restrict__ bf1, const float* __restrict__ bf2,
    const float* __restrict__ bf3, float* __restrict__ out) {
  int wv = threadIdx.x >> 6, lane = threadIdx.x & 63;
  int src = blockIdx.x * 4 + wv;
  int h = lane & 15, eslot = lane >> 4;
  int lo = off[src];
  int deg = off[src + 1] - lo;
  const uint4* qp = (const uint4*)(qkv + (size_t)src * 768 + h * 16);
  uint4 q0 = qp[0], q1 = qp[1];
  float exsum = 0.f, a0 = 0.f, a1 = 0.f, a2 = 0.f;
  for (int ei = eslot; ei < deg; ei += 4) {
    int2 d_e = de[lo + ei];
    const uint4* kp = (const uint4*)(qkv + (size_t)d_e.x * 768 + 256 + h * 16);
    float d = dot8(q0, kp[0]) + dot8(q1, kp[1]);
    float ex = __expf(d + bias[(size_t)d_e.y * HEADS + h]);
    exsum += ex;
    const float* vp = vw + (size_t)d_e.x * 48 + h * 3;
    const float* dp = edge_diff + (size_t)d_e.y * 3;
    a0 += ex * vp[0] * dp[0];
    a1 += ex * vp[1] * dp[1];
    a2 += ex * vp[2] * dp[2];
  }
  exsum += __shfl_xor(exsum, 16);
  exsum += __shfl_xor(exsum, 32);
  float rden = (exsum > 0.f) ? 1.0f / exsum : 0.f;
  a0 *= rden; a1 *= rden; a2 *= rden;
  #pragma unroll
  for (int o = 1; o < 64; o <<= 1) {
    a0 += __shfl_xor(a0, o);
    a1 += __shfl_xor(a1, o);
    a2 += __shfl_xor(a2, o);
  }
  if (lane == 0) {
    out[src * 3 + 0] = a0 + bf1[0];
    out[src * 3 + 1] = a1 + bf2[0];
    out[src * 3 + 2] = a2 + bf3[0];
  }
}

// ==================================================================
extern "C" void kernel_launch(void* const* d_in, const int* in_sizes, int n_in,
                              void* d_out, int out_size, void* d_ws,
                              size_t ws_size, hipStream_t stream) {
  const float* query      = (const float*)d_in[0];
  const int*   edge_index = (const int*)d_in[1];
  const float* edge_diff  = (const float*)d_in[2];
  const float* pair       = (const float*)d_in[3];
  const float* ln_w       = (const float*)d_in[4];
  const float* ln_b       = (const float*)d_in[5];
  const float* pln_w      = (const float*)d_in[6];
  const float* pln_b      = (const float*)d_in[7];
  const float* Wq         = (const float*)d_in[8];
  const float* Wk         = (const float*)d_in[9];
  const float* Wv         = (const float*)d_in[10];
  const float* Wb         = (const float*)d_in[11];
  const float* bb         = (const float*)d_in[12];
  const float* Wf1        = (const float*)d_in[13];
  const float* bf1        = (const float*)d_in[14];
  const float* Wf2        = (const float*)d_in[15];
  const float* bf2        = (const float*)d_in[16];
  const float* Wf3        = (const float*)d_in[17];
  const float* bf3        = (const float*)d_in[18];

  char* ws = (char*)d_ws;
  u16*   qkv   = (u16*)(ws + WS_QKV);
  u16*   qn    = (u16*)(ws + WS_QN);
  u16*   Wbf   = (u16*)(ws + WS_WBF);
  u16*   WWbf  = (u16*)(ws + WS_WW);
  float* c0    = (float*)(ws + WS_C0);
  float* c1    = (float*)(ws + WS_C1);
  float* bias  = (float*)(ws + WS_BIAS);
  float* vw    = (float*)(ws + WS_VW);
  int*   counts= (int*)(ws + WS_CNT);
  int*   cur   = (int*)(ws + WS_CUR);
  int*   off   = (int*)(ws + WS_OFF);
  int2*  de    = (int2*)(ws + WS_DE);
  float* out   = (float*)d_out;

  k1_pre_kernel<<<5193, 256, 0, stream>>>(query, ln_w, ln_b, qn, counts, cur,
                                          Wq, Wk, Wv, Wbf, pln_w, pln_b, Wb,
                                          bb, WWbf, c0, c1);
  k2_gemm_hist_kernel<<<4538, 256, 0, stream>>>(qn, Wbf, qkv, edge_index,
                                                counts);
  scan_kernel<<<1, 1024, 0, stream>>>(counts, off);
  k4_bias_vw_scatter_kernel<<<5157, 256, 0, stream>>>(
      pair, WWbf, c0, c1, bias, qkv, Wf1, Wf2, Wf3, vw, edge_index, off, cur,
      de);
  seg_attn_kernel<<<N_NODE / 4, 256, 0, stream>>>(qkv, bias, off, de, vw,
                                                  edge_diff, bf1, bf2, bf3,
                                                  out);
}

// Round 7
// 290.126 us; speedup vs baseline: 1.1003x; 1.0197x over previous
//
#include <hip/hip_runtime.h>
#include <math.h>

#define N_NODE 20000
#define N_EDGE 200000
#define EMBED 256
#define PAIR 128
#define HEADS 16
#define HEAD_DIM 16
#define SCALING 0.25f
#define LNEPS 1e-5f

typedef unsigned short u16;
typedef unsigned int u32;
typedef __attribute__((ext_vector_type(8))) short bf16x8;
typedef __attribute__((ext_vector_type(4))) float f32x4;

// ---------------- workspace layout (bytes) ----------------
#define WS_QKV   0            // qkv_bf : 20000*768*2  = 30,720,000 (q scaled)
#define WS_QN    30720000     // qn_bf  : 20000*256*2  = 10,240,000
#define WS_WBF   40960000     // Wbf    : 768*256*2    =    393,216
#define WS_WW    41353216     // WW_bf  : 16*128*2     =      4,096
#define WS_C0    41357312     // c0     : 16*4 (pad 64)
#define WS_C1    41357376     // c1     : 16*4 (pad 64)
#define WS_BIAS  41357440     // bias   : 200000*16*4  = 12,800,000
#define WS_VW    54157440     // vw     : 20000*48*4   =  3,840,000
#define WS_CNT   57997440     // counts : 20000*4
#define WS_CUR   58077440     // cursor : 20000*4
#define WS_OFF   58157440     // off    : 20001*4 (pad to 80064)
#define WS_DE    58237504     // {dst,e}: 200000*8     =  1,600,000

__device__ __forceinline__ u16 f2bf(float f) {
  u32 u = __float_as_uint(f);
  u32 r = (u + 0x7FFFu + ((u >> 16) & 1u)) >> 16;
  return (u16)r;
}
__device__ __forceinline__ float bl(u32 u) { return __uint_as_float(u << 16); }
__device__ __forceinline__ float bh(u32 u) { return __uint_as_float(u & 0xFFFF0000u); }

__device__ __forceinline__ float dot8(uint4 a, uint4 b) {
  float s = bl(a.x) * bl(b.x) + bh(a.x) * bh(b.x);
  s += bl(a.y) * bl(b.y) + bh(a.y) * bh(b.y);
  s += bl(a.z) * bl(b.z) + bh(a.z) * bh(b.z);
  s += bl(a.w) * bl(b.w) + bh(a.w) * bh(b.w);
  return s;
}

// ==================================================================
// K1: block-partitioned — [0,5000): ln_qn (+zero counts/cur);
// [5000,5192): wcvt; 5192: prep.
__global__ __launch_bounds__(256) void k1_pre_kernel(
    const float* __restrict__ query, const float* __restrict__ ln_w,
    const float* __restrict__ ln_b, u16* __restrict__ qn,
    int* __restrict__ counts, int* __restrict__ cur,
    const float* __restrict__ Wq, const float* __restrict__ Wk,
    const float* __restrict__ Wv, u16* __restrict__ Wbf,
    const float* __restrict__ pln_w, const float* __restrict__ pln_b,
    const float* __restrict__ Wb, const float* __restrict__ bb,
    u16* __restrict__ WWbf, float* __restrict__ c0, float* __restrict__ c1) {
  int bid = blockIdx.x;
  if (bid < 5000) {
    int z = bid * 256 + threadIdx.x;
    if (z < N_NODE) { counts[z] = 0; cur[z] = 0; }
    int node = bid * 4 + (threadIdx.x >> 6);
    int lane = threadIdx.x & 63;
    float4 a = *(const float4*)(query + (size_t)node * EMBED + lane * 4);
    float s = a.x + a.y + a.z + a.w;
    float s2 = a.x * a.x + a.y * a.y + a.z * a.z + a.w * a.w;
    #pragma unroll
    for (int off = 32; off > 0; off >>= 1) {
      s += __shfl_xor(s, off);
      s2 += __shfl_xor(s2, off);
    }
    float m = s * (1.0f / EMBED);
    float r = rsqrtf(s2 * (1.0f / EMBED) - m * m + LNEPS);
    float4 w4 = *(const float4*)(ln_w + lane * 4);
    float4 b4 = *(const float4*)(ln_b + lane * 4);
    ushort4 st;
    st.x = f2bf((a.x - m) * r * w4.x + b4.x);
    st.y = f2bf((a.y - m) * r * w4.y + b4.y);
    st.z = f2bf((a.z - m) * r * w4.z + b4.z);
    st.w = f2bf((a.w - m) * r * w4.w + b4.w);
    *(ushort4*)(qn + (size_t)node * EMBED + lane * 4) = st;
  } else if (bid < 5192) {
    int g4 = (bid - 5000) * 256 + threadIdx.x;
    int idx = g4 * 4;
    const float* src = (idx < 65536) ? Wq : (idx < 131072 ? Wk : Wv);
    float4 v = *(const float4*)(src + (idx & 65535));
    ushort4 st = {f2bf(v.x), f2bf(v.y), f2bf(v.z), f2bf(v.w)};
    *(ushort4*)(Wbf + idx) = st;
  } else if (threadIdx.x < 64) {
    int l = threadIdx.x;
    for (int h = 0; h < HEADS; h++) {
      int i0 = l * 2;
      float wb0 = Wb[h * PAIR + i0], wb1 = Wb[h * PAIR + i0 + 1];
      float ww0 = pln_w[i0] * wb0, ww1 = pln_w[i0 + 1] * wb1;
      WWbf[h * PAIR + i0] = f2bf(ww0);
      WWbf[h * PAIR + i0 + 1] = f2bf(ww1);
      float s1 = ww0 + ww1;
      float s0 = pln_b[i0] * wb0 + pln_b[i0 + 1] * wb1;
      #pragma unroll
      for (int off = 32; off > 0; off >>= 1) {
        s1 += __shfl_xor(s1, off);
        s0 += __shfl_xor(s0, off);
      }
      if (l == 0) {
        c1[h] = s1;
        c0[h] = s0 + bb[h];
      }
    }
  }
}

// ==================================================================
// K2: block-partitioned — [0,942): qkv GEMM, m93-style 128x128 block,
// 4 waves each computing 64x64 (4x4 MFMA tiles), BK=64, padded stride 72;
// [942,1724): hist. Accumulation order over K identical to R6 (8 chunks
// of 32) -> bit-identical output.
#define BKP 72
__global__ __launch_bounds__(256, 2) void k2_gemm_hist_kernel(
    const u16* __restrict__ qn, const u16* __restrict__ Wbf,
    u16* __restrict__ qkv, const int* __restrict__ edge_index,
    int* __restrict__ counts) {
  __shared__ u16 As[128 * BKP];
  __shared__ u16 Bs[128 * BKP];
  int bid = blockIdx.x;
  if (bid >= 942) {
    int e = (bid - 942) * 256 + threadIdx.x;
    if (e < N_EDGE) atomicAdd(&counts[edge_index[e * 2]], 1);
    return;
  }
  int bx = bid % 157, by = bid / 157;
  int t = threadIdx.x;
  int wv = t >> 6, lane = t & 63;
  int quad = lane >> 4, l16 = lane & 15;
  int row0 = bx * 128, col0 = by * 128;
  int mt = (wv >> 1) * 64, nt = (wv & 1) * 64;

  f32x4 acc[4][4];
  #pragma unroll
  for (int im = 0; im < 4; im++)
    #pragma unroll
    for (int in_ = 0; in_ < 4; in_++) acc[im][in_] = (f32x4){0.f, 0.f, 0.f, 0.f};

  for (int it = 0; it < 4; it++) {
    int k0 = it * 64;
    // stage A and B: 128 rows x 64 k each; 4 uint4 per thread per matrix
    #pragma unroll
    for (int j = 0; j < 4; j++) {
      int L = j * 256 + t;          // 0..1023
      int row = L >> 3, slot = L & 7;
      int ra = min(row0 + row, N_NODE - 1);
      uint4 va = *(const uint4*)(qn + (size_t)ra * 256 + k0 + slot * 8);
      *(uint4*)(&As[row * BKP + slot * 8]) = va;
      uint4 vb = *(const uint4*)(Wbf + (size_t)(col0 + row) * 256 + k0 + slot * 8);
      *(uint4*)(&Bs[row * BKP + slot * 8]) = vb;
    }
    __syncthreads();
    #pragma unroll
    for (int s = 0; s < 2; s++) {
      int ko = s * 32 + quad * 8;
      bf16x8 af[4], bf[4];
      #pragma unroll
      for (int im = 0; im < 4; im++)
        af[im] = *(const bf16x8*)(&As[(mt + im * 16 + l16) * BKP + ko]);
      #pragma unroll
      for (int in_ = 0; in_ < 4; in_++)
        bf[in_] = *(const bf16x8*)(&Bs[(nt + in_ * 16 + l16) * BKP + ko]);
      #pragma unroll
      for (int im = 0; im < 4; im++)
        #pragma unroll
        for (int in_ = 0; in_ < 4; in_++)
          acc[im][in_] = __builtin_amdgcn_mfma_f32_16x16x32_bf16(
              af[im], bf[in_], acc[im][in_], 0, 0, 0);
    }
    __syncthreads();
  }
  #pragma unroll
  for (int im = 0; im < 4; im++) {
    #pragma unroll
    for (int in_ = 0; in_ < 4; in_++) {
      int gcol = col0 + nt + in_ * 16 + l16;
      float scale = (gcol < 256) ? SCALING : 1.0f;
      #pragma unroll
      for (int r = 0; r < 4; r++) {
        int grow = row0 + mt + im * 16 + quad * 4 + r;
        if (grow < N_NODE)
          qkv[(size_t)grow * 768 + gcol] = f2bf(acc[im][in_][r] * scale);
      }
    }
  }
}

// ==================================================================
// K3: exclusive scan of counts (20000) -> off[0..20000]. Single block.
__global__ __launch_bounds__(1024) void scan_kernel(
    const int* __restrict__ counts, int* __restrict__ off) {
  __shared__ int part[1024];
  int t = threadIdx.x;
  int loc[20];
  int s = 0;
  #pragma unroll
  for (int i = 0; i < 20; i++) {
    int idx = t * 20 + i;
    int v = (idx < N_NODE) ? counts[idx] : 0;
    loc[i] = s;
    s += v;
  }
  part[t] = s;
  __syncthreads();
  int x = s;
  for (int o = 1; o < 1024; o <<= 1) {
    int y = (t >= o) ? part[t - o] : 0;
    __syncthreads();
    x += y;
    part[t] = x;
    __syncthreads();
  }
  int excl = x - s;
  #pragma unroll
  for (int i = 0; i < 20; i++) {
    int idx = t * 20 + i;
    if (idx < N_NODE) off[idx] = excl + loc[i];
  }
  if (t == 0) off[N_NODE] = N_EDGE;
}

// ==================================================================
// K4: block-partitioned — [0,3125): pair_bias (R2-proven);
// [3125,4375): vw (R2-proven); [4375,5157): scatter.
#define PP 136
__global__ __launch_bounds__(256) void k4_bias_vw_scatter_kernel(
    const float* __restrict__ pair, const u16* __restrict__ WWbf,
    const float* __restrict__ c0g, const float* __restrict__ c1g,
    float* __restrict__ bias, const u16* __restrict__ qkv,
    const float* __restrict__ Wf1, const float* __restrict__ Wf2,
    const float* __restrict__ Wf3, float* __restrict__ vw,
    const int* __restrict__ edge_index, const int* __restrict__ off,
    int* __restrict__ cur, int2* __restrict__ de) {
  __shared__ u16 Ps[64 * PP];
  __shared__ u16 WWs[16 * PP];
  __shared__ float ms[64], rs[64], c0s[16], c1s[16];
  int bid = blockIdx.x;
  int t = threadIdx.x;
  if (bid >= 4375) {
    int e = (bid - 4375) * 256 + t;
    if (e < N_EDGE) {
      int src = edge_index[e * 2 + 0];
      int dst = edge_index[e * 2 + 1];
      int pos = off[src] + atomicAdd(&cur[src], 1);
      de[pos] = make_int2(dst, e);
    }
    return;
  }
  if (bid >= 3125) {
    int gid = (bid - 3125) * 256 + t;  // 320000
    int n = gid >> 4, h = gid & 15;
    const uint4* vp = (const uint4*)(qkv + (size_t)n * 768 + 512 + h * 16);
    uint4 va = vp[0], vb = vp[1];
    float v[16];
    v[0] = bl(va.x); v[1] = bh(va.x); v[2] = bl(va.y); v[3] = bh(va.y);
    v[4] = bl(va.z); v[5] = bh(va.z); v[6] = bl(va.w); v[7] = bh(va.w);
    v[8] = bl(vb.x); v[9] = bh(vb.x); v[10] = bl(vb.y); v[11] = bh(vb.y);
    v[12] = bl(vb.z); v[13] = bh(vb.z); v[14] = bl(vb.w); v[15] = bh(vb.w);
    const float* wf[3] = {Wf1 + h * 16, Wf2 + h * 16, Wf3 + h * 16};
    #pragma unroll
    for (int c = 0; c < 3; c++) {
      float s = 0.f;
      #pragma unroll
      for (int d = 0; d < 16; d++) s += v[d] * wf[c][d];
      vw[(size_t)n * 48 + h * 3 + c] = s;
    }
    return;
  }
  // ---- pair_bias ----
  int wv = t >> 6, lane = t & 63;
  int quad = lane >> 4, l16 = lane & 15;
  int e0 = bid * 64;
  #pragma unroll
  for (int j = 0; j < 8; j++) {
    int L = j * 256 + t;
    int row = L >> 5, slot = L & 31;
    float4 p = *(const float4*)(pair + (size_t)(e0 + row) * PAIR + slot * 4);
    ushort4 st = {f2bf(p.x), f2bf(p.y), f2bf(p.z), f2bf(p.w)};
    *(ushort4*)(&Ps[row * PP + slot * 4]) = st;
  }
  #pragma unroll
  for (int j = 0; j < 2; j++) {
    int L = j * 256 + t;
    int row = L >> 5, slot = L & 31;
    ushort4 w = *(const ushort4*)(WWbf + row * PAIR + slot * 4);
    *(ushort4*)(&WWs[row * PP + slot * 4]) = w;
  }
  if (t < 16) {
    c0s[t] = c0g[t];
    c1s[t] = c1g[t];
  }
  __syncthreads();
  {
    int row = t >> 2, qq = t & 3;
    float s = 0.f, s2 = 0.f;
    #pragma unroll
    for (int jj = 0; jj < 8; jj++) {
      ushort4 u = *(const ushort4*)(&Ps[row * PP + (qq * 8 + jj) * 4]);
      float x0 = __uint_as_float((u32)u.x << 16);
      float x1 = __uint_as_float((u32)u.y << 16);
      float x2 = __uint_as_float((u32)u.z << 16);
      float x3 = __uint_as_float((u32)u.w << 16);
      s += x0 + x1 + x2 + x3;
      s2 += x0 * x0 + x1 * x1 + x2 * x2 + x3 * x3;
    }
    s += __shfl_xor(s, 1); s += __shfl_xor(s, 2);
    s2 += __shfl_xor(s2, 1); s2 += __shfl_xor(s2, 2);
    if (qq == 0) {
      float m = s * (1.0f / PAIR);
      ms[row] = m;
      rs[row] = rsqrtf(s2 * (1.0f / PAIR) - m * m + LNEPS);
    }
  }
  __syncthreads();
  f32x4 acc = (f32x4){0.f, 0.f, 0.f, 0.f};
  #pragma unroll
  for (int sk = 0; sk < 4; sk++) {
    int ko = sk * 32 + quad * 8;
    bf16x8 a = *(const bf16x8*)(&Ps[(wv * 16 + l16) * PP + ko]);
    bf16x8 b = *(const bf16x8*)(&WWs[l16 * PP + ko]);
    acc = __builtin_amdgcn_mfma_f32_16x16x32_bf16(a, b, acc, 0, 0, 0);
  }
  #pragma unroll
  for (int r = 0; r < 4; r++) {
    int el = wv * 16 + quad * 4 + r;
    float bv = rs[el] * (acc[r] - ms[el] * c1s[l16]) + c0s[l16];
    bias[(size_t)(e0 + el) * HEADS + l16] = bv;
  }
}

// ==================================================================
// K5: segmented attention, single pass (R5-proven).
__global__ __launch_bounds__(256) void seg_attn_kernel(
    const u16* __restrict__ qkv, const float* __restrict__ bias,
    const int* __restrict__ off, const int2* __restrict__ de,
    const float* __restrict__ vw, const float* __restrict__ edge_diff,
    const float* __restrict__ bf1, const float* __restrict__ bf2,
    const float* __restrict__ bf3, float* __restrict__ out) {
  int wv = threadIdx.x >> 6, lane = threadIdx.x & 63;
  int src = blockIdx.x * 4 + wv;
  int h = lane & 15, eslot = lane >> 4;
  int lo = off[src];
  int deg = off[src + 1] - lo;
  const uint4* qp = (const uint4*)(qkv + (size_t)src * 768 + h * 16);
  uint4 q0 = qp[0], q1 = qp[1];
  float exsum = 0.f, a0 = 0.f, a1 = 0.f, a2 = 0.f;
  for (int ei = eslot; ei < deg; ei += 4) {
    int2 d_e = de[lo + ei];
    const uint4* kp = (const uint4*)(qkv + (size_t)d_e.x * 768 + 256 + h * 16);
    float d = dot8(q0, kp[0]) + dot8(q1, kp[1]);
    float ex = __expf(d + bias[(size_t)d_e.y * HEADS + h]);
    exsum += ex;
    const float* vp = vw + (size_t)d_e.x * 48 + h * 3;
    const float* dp = edge_diff + (size_t)d_e.y * 3;
    a0 += ex * vp[0] * dp[0];
    a1 += ex * vp[1] * dp[1];
    a2 += ex * vp[2] * dp[2];
  }
  exsum += __shfl_xor(exsum, 16);
  exsum += __shfl_xor(exsum, 32);
  float rden = (exsum > 0.f) ? 1.0f / exsum : 0.f;
  a0 *= rden; a1 *= rden; a2 *= rden;
  #pragma unroll
  for (int o = 1; o < 64; o <<= 1) {
    a0 += __shfl_xor(a0, o);
    a1 += __shfl_xor(a1, o);
    a2 += __shfl_xor(a2, o);
  }
  if (lane == 0) {
    out[src * 3 + 0] = a0 + bf1[0];
    out[src * 3 + 1] = a1 + bf2[0];
    out[src * 3 + 2] = a2 + bf3[0];
  }
}

// ==================================================================
extern "C" void kernel_launch(void* const* d_in, const int* in_sizes, int n_in,
                              void* d_out, int out_size, void* d_ws,
                              size_t ws_size, hipStream_t stream) {
  const float* query      = (const float*)d_in[0];
  const int*   edge_index = (const int*)d_in[1];
  const float* edge_diff  = (const float*)d_in[2];
  const float* pair       = (const float*)d_in[3];
  const float* ln_w       = (const float*)d_in[4];
  const float* ln_b       = (const float*)d_in[5];
  const float* pln_w      = (const float*)d_in[6];
  const float* pln_b      = (const float*)d_in[7];
  const float* Wq         = (const float*)d_in[8];
  const float* Wk         = (const float*)d_in[9];
  const float* Wv         = (const float*)d_in[10];
  const float* Wb         = (const float*)d_in[11];
  const float* bb         = (const float*)d_in[12];
  const float* Wf1        = (const float*)d_in[13];
  const float* bf1        = (const float*)d_in[14];
  const float* Wf2        = (const float*)d_in[15];
  const float* bf2        = (const float*)d_in[16];
  const float* Wf3        = (const float*)d_in[17];
  const float* bf3        = (const float*)d_in[18];

  char* ws = (char*)d_ws;
  u16*   qkv   = (u16*)(ws + WS_QKV);
  u16*   qn    = (u16*)(ws + WS_QN);
  u16*   Wbf   = (u16*)(ws + WS_WBF);
  u16*   WWbf  = (u16*)(ws + WS_WW);
  float* c0    = (float*)(ws + WS_C0);
  float* c1    = (float*)(ws + WS_C1);
  float* bias  = (float*)(ws + WS_BIAS);
  float* vw    = (float*)(ws + WS_VW);
  int*   counts= (int*)(ws + WS_CNT);
  int*   cur   = (int*)(ws + WS_CUR);
  int*   off   = (int*)(ws + WS_OFF);
  int2*  de    = (int2*)(ws + WS_DE);
  float* out   = (float*)d_out;

  k1_pre_kernel<<<5193, 256, 0, stream>>>(query, ln_w, ln_b, qn, counts, cur,
                                          Wq, Wk, Wv, Wbf, pln_w, pln_b, Wb,
                                          bb, WWbf, c0, c1);
  k2_gemm_hist_kernel<<<1724, 256, 0, stream>>>(qn, Wbf, qkv, edge_index,
                                                counts);
  scan_kernel<<<1, 1024, 0, stream>>>(counts, off);
  k4_bias_vw_scatter_kernel<<<5157, 256, 0, stream>>>(
      pair, WWbf, c0, c1, bias, qkv, Wf1, Wf2, Wf3, vw, edge_index, off, cur,
      de);
  seg_attn_kernel<<<N_NODE / 4, 256, 0, stream>>>(qkv, bias, off, de, vw,
                                                  edge_diff, bf1, bf2, bf3,
                                                  out);
}